// Round 8
// baseline (276.505 us; speedup 1.0000x reference)
//
#include <hip/hip_runtime.h>

#define TLEN 512
#define HID  64

typedef _Float16 half8 __attribute__((ext_vector_type(8)));
typedef float    f32x4 __attribute__((ext_vector_type(4)));

__device__ __forceinline__ float rcp_fast(float x) { return __builtin_amdgcn_rcpf(x); }
__device__ __forceinline__ float exp2_fast(float x) {
#if __has_builtin(__builtin_amdgcn_exp2f)
    return __builtin_amdgcn_exp2f(x);
#else
    float r; asm("v_exp_f32 %0, %1" : "=v"(r) : "v"(x)); return r;
#endif
}

// R19: anti-phase role-split. R15 (472 issue, 264 dead) vs R18 (772 issue,
// 39 dead) showed the win is LOW issue + stagger. The 8 batch rows are
// independent recurrences: waves 0-3 own rows 0-3 (group A), waves 4-7 own
// rows 4-7 (group B), half a step out of phase. Per barrier interval one
// group does read+MFMA(k) while the other does cell+write(k) from register-
// held MFMA results; swap next interval. SIMD siblings (w, w+4) are thus
// always on OPPOSITE pipes (MFMA vs VALU/trans co-schedule, m114): the cell
// hides in the MFMA/ds_read shadow. dup4 (group = 4 real rows x 4 dup) ->
// MFMA 272 cyc/SIMD-step (= R18), census 1 act/lane (invariant), cell =
// R14/R15 merged-ratio (5 exp2 + 2 rcp). Single h-buffer per group
// (write/read barrier-separated), stride 80 (R18: 0 conflicts).
__global__ __launch_bounds__(512) __attribute__((amdgpu_waves_per_eu(2, 2)))
void lstm_pipe(const float* __restrict__ x,
               const float* __restrict__ W_ih,
               const float* __restrict__ W_hh,
               const float* __restrict__ b_ih,
               const float* __restrict__ b_hh,
               const float* __restrict__ W_d,
               const float* __restrict__ b_d,
               float* __restrict__ out) {
    __shared__ __align__(16) float    xs[8][516];   // 8 x rows
    __shared__ __align__(16) _Float16 hb[2][4][80]; // [group][row][unit], pad 80

    const int tid = threadIdx.x;
    const int L   = tid & 63;
    const int w   = tid >> 6;        // 0..7
    const int isA = (w < 4) ? 1 : 0; // group A = waves 0-3 (rows 0-3)
    const int wl  = w & 3;           // wave index within group
    const int gi  = 1 - isA;         // group index (A=0, B=1)
    const int r0  = blockIdx.x * 8;

    // ---- stage x rows (float4) ----
    for (int i = tid; i < 8 * 128; i += 512) {
        const int r = i >> 7, t4 = (i & 127) * 4;
        *(float4*)&xs[r][t4] = *(const float4*)&x[(size_t)(r0 + r) * TLEN + t4];
    }
    // ---- zero both h buffers (h(-1) = 0) ----
    for (int i = tid; i < 2 * 4 * 80; i += 512)
        ((_Float16*)hb)[i] = (_Float16)0.0f;

    const float K  = 1.44269504f;    // log2 e
    const float K2 = 2.0f * K;

    // ---- resident A-frags af[tt][q]: A[m][k], m=L&15, k=32q+(L>>4)*8+i ----
    // tile tt rows: unit ul = 16wl + 4tt + (m>>2), gate m&3 (R18-verified map)
    // Gate scale folded into A: s = -K (i,f,o), +2K (g).
    half8 af[4][2];
    {
        const int m  = L & 15;
        const int g  = m & 3;
        const int kb = (L >> 4) * 8;
        const float sg = (g == 2) ? K2 : -K;
#pragma unroll
        for (int tt = 0; tt < 4; ++tt) {
            const int uu = 16 * wl + 4 * tt + (m >> 2);
            const float* row = &W_hh[(size_t)(g * HID + uu) * HID];
#pragma unroll
            for (int q = 0; q < 2; ++q) {
                const float* p = row + 32 * q + kb;
                half8 hf;
#pragma unroll
                for (int i = 0; i < 8; ++i) hf[i] = (_Float16)(sg * p[i]);
                af[tt][q] = hf;
            }
        }
    }

    // ---- lane act role: col c -> row b (in group), dup selects tile ----
    const int c   = L & 15;
    const int b   = c & 3;
    const int dup = c >> 2;                  // 0..3
    const int u   = 16 * wl + 4 * dup + (L >> 4);
    const bool d1 = dup & 1;
    const bool d2 = dup & 2;
    // per group: 4 waves x 64 lanes <-> 4 rows x 64 units: 1 act/lane.

    // pre-gate params, pre-scaled into exp2 domain
    float wih[4], bias[4];
#pragma unroll
    for (int g = 0; g < 4; ++g) {
        const float s = (g == 2) ? K2 : -K;
        wih[g]  = s * W_ih[g * HID + u];
        bias[g] = s * (b_ih[g * HID + u] + b_hh[g * HID + u]);
    }

    const float* xrow = &xs[gi * 4 + b][0];
    const int koff = (L >> 4) * 8;
    const _Float16* hrd = &hb[gi][b][0]; // own-group read base
    _Float16*       hwr = &hb[gi][0][0];
    const int widx = b * 80 + u;
    const f32x4 zero = {0.0f, 0.0f, 0.0f, 0.0f};

    f32x4 t0, t1, t2, t3;            // gate accs, held across the barrier
    float S = 0.0f;                  // state: S = 2K * c

    __syncthreads();

    auto mfma_phase = [&]() {
        const half8 b0 = *(const half8*)(hrd + koff);
        const half8 b1 = *(const half8*)(hrd + koff + 32);
        t0 = __builtin_amdgcn_mfma_f32_16x16x32_f16(af[0][0], b0, zero, 0, 0, 0);
        t1 = __builtin_amdgcn_mfma_f32_16x16x32_f16(af[1][0], b0, zero, 0, 0, 0);
        t2 = __builtin_amdgcn_mfma_f32_16x16x32_f16(af[2][0], b0, zero, 0, 0, 0);
        t3 = __builtin_amdgcn_mfma_f32_16x16x32_f16(af[3][0], b0, zero, 0, 0, 0);
        t0 = __builtin_amdgcn_mfma_f32_16x16x32_f16(af[0][1], b1, t0, 0, 0, 0);
        t1 = __builtin_amdgcn_mfma_f32_16x16x32_f16(af[1][1], b1, t1, 0, 0, 0);
        t2 = __builtin_amdgcn_mfma_f32_16x16x32_f16(af[2][1], b1, t2, 0, 0, 0);
        t3 = __builtin_amdgcn_mfma_f32_16x16x32_f16(af[3][1], b1, t3, 0, 0, 0);
    };

    auto cell_phase = [&](int k) {
        const float xt = xrow[k];    // scalar LDS read; hidden under select
        // 2-bit tile select (12 cndmask)
        f32x4 dS;
#pragma unroll
        for (int r = 0; r < 4; ++r) {
            const float a01 = d1 ? t1[r] : t0[r];
            const float a23 = d1 ? t3[r] : t2[r];
            dS[r] = d2 ? a23 : a01;
        }
        // args already scaled: -K*a (i,f,o), +2K*a (g)
        const float ei = exp2_fast(fmaf(xt, wih[0], bias[0]) + dS[0]);
        const float ef = exp2_fast(fmaf(xt, wih[1], bias[1]) + dS[1]);
        const float eg = exp2_fast(fmaf(xt, wih[2], bias[2]) + dS[2]);
        const float eo = exp2_fast(fmaf(xt, wih[3], bias[3]) + dS[3]);
        // merged-ratio cell on S = 2K*c: 2 rcp total
        const float A1  = 1.0f + ei;
        const float B1  = 1.0f + eg;
        const float E1  = 1.0f + ef;
        const float C1K = fmaf(eg, K2, -K2);     // 2K*(eg-1)
        const float Pig = A1 * B1;
        const float Dde = E1 * Pig;
        const float CEK = C1K * E1;
        const float num = fmaf(S, Pig, CEK);
        S = num * rcp_fast(Dde);                 // S' = 2K*(gf*c + gi*gg)
        const float ec = exp2_fast(S);
        const float F1 = 1.0f + eo;
        const float G1 = 1.0f + ec;
        const float H1 = ec - 1.0f;
        const float hv = H1 * rcp_fast(F1 * G1); // go * tanh(c')
        hwr[widx] = (_Float16)hv;
    };

    // ---- software-pipelined main loop: 2 intervals per time-step ----
    // interval 2k  : A mfma(k)   | B cell(k-1)+write
    // interval 2k+1: A cell(k)+w | B mfma(k)
    if (isA) mfma_phase();           // prologue: A mfma(0) on h=0
    __syncthreads();
    for (int k = 0; k < TLEN - 1; ++k) {
        if (isA) cell_phase(k); else mfma_phase();
        __syncthreads();
        if (isA) mfma_phase(); else cell_phase(k);
        __syncthreads();
    }
    if (isA) cell_phase(TLEN - 1); else mfma_phase();
    __syncthreads();
    if (!isA) cell_phase(TLEN - 1);  // epilogue: B finishes step 511
    __syncthreads();

    // ---- epilogue: wave w reduces global row w (group w>>2, row w&3) ----
    float pv = (float)hb[w >> 2][w & 3][L] * W_d[L];
#pragma unroll
    for (int off = 32; off > 0; off >>= 1)
        pv += __shfl_xor(pv, off, 64);
    if (L == 0)
        out[r0 + w] = pv + b_d[0];
}

extern "C" void kernel_launch(void* const* d_in, const int* in_sizes, int n_in,
                              void* d_out, int out_size, void* d_ws, size_t ws_size,
                              hipStream_t stream) {
    const float* x    = (const float*)d_in[0];
    const float* W_ih = (const float*)d_in[1];
    const float* W_hh = (const float*)d_in[2];
    const float* b_ih = (const float*)d_in[3];
    const float* b_hh = (const float*)d_in[4];
    const float* W_d  = (const float*)d_in[5];
    const float* b_d  = (const float*)d_in[6];
    float* out = (float*)d_out;

    dim3 grid(256);    // 1 block/CU, 8 rows each
    dim3 block(512);   // 8 waves; SIMD siblings (w, w+4) are in opposite roles
    lstm_pipe<<<grid, block, 0, stream>>>(x, W_ih, W_hh, b_ih, b_hh, W_d, b_d, out);
}

// Round 9
// 205.184 us; speedup vs baseline: 1.3476x; 1.3476x over previous
//
#include <hip/hip_runtime.h>

#define TLEN 512
#define HID  64

typedef _Float16 half8 __attribute__((ext_vector_type(8)));
typedef float    f32x4 __attribute__((ext_vector_type(4)));

__device__ __forceinline__ float rcp_fast(float x) { return __builtin_amdgcn_rcpf(x); }
__device__ __forceinline__ float exp2_fast(float x) {
#if __has_builtin(__builtin_amdgcn_exp2f)
    return __builtin_amdgcn_exp2f(x);
#else
    float r; asm("v_exp_f32 %0, %1" : "=v"(r) : "v"(x)); return r;
#endif
}

// R20 = R15 (157.6 us, best) + serial-prefix pipelining. R15 is census-
// optimal (dup2 MFMA floor, 7-trans cell floor, 1 act/lane); its step =
// 736 cyc with ~264 dead on the in-phase chain. The 8 pre-gate fmas (C_in,
// x-only dependence) are moved OFF the post-barrier critical prefix: step k
// computes step k+1's C_in during its own exp2-latency shadow. Next-quad x
// load hoisted to quad top (max lead). b0-only MFMA pair kept first so the
// compiler's lgkmcnt(1) overlaps MFMA with the second ds_read.
// No setprio, no role-split, no 32x32, no 2-blk dup4 (R12/R16/R17/R19 all
// regressed; models in round notes).
__global__ __launch_bounds__(512) __attribute__((amdgpu_waves_per_eu(2, 2)))
void lstm_r20(const float* __restrict__ x,
              const float* __restrict__ W_ih,
              const float* __restrict__ W_hh,
              const float* __restrict__ b_ih,
              const float* __restrict__ b_hh,
              const float* __restrict__ W_d,
              const float* __restrict__ b_d,
              float* __restrict__ out) {
    __shared__ __align__(16) float    xs[8][516];     // 8 x rows (516: +4 overread pad)
    __shared__ __align__(16) _Float16 hbuf[2][8][80]; // ping-pong h, pad 80

    const int tid = threadIdx.x;
    const int L   = tid & 63;
    const int w   = tid >> 6;        // wave 0..7, owns units [8w, 8w+8)
    const int r0  = blockIdx.x * 8;

    // ---- stage x rows (float4) ----
    for (int i = tid; i < 8 * 128; i += 512) {
        const int r = i >> 7, t4 = (i & 127) * 4;
        *(float4*)&xs[r][t4] = *(const float4*)&x[(size_t)(r0 + r) * TLEN + t4];
    }
    // ---- zero both h buffers (h0 = 0) ----
    for (int i = tid; i < 2 * 8 * 80; i += 512)
        ((_Float16*)hbuf)[i] = (_Float16)0.0f;

    const float K  = 1.44269504f;    // log2 e
    const float K2 = 2.0f * K;

    // ---- resident A-frags: A[m][k], m=L&15, k=32q+(L>>4)*8+i ----
    // tile tt -> unit 8w+4tt+(m>>2), gate m&3 (i,f,g,o)
    // Gate scale folded into A: s = -K (i,f,o), +2K (g).
    half8 af[2][2];
    {
        const int m = L & 15;
        const int g = m & 3;
        const int kb = (L >> 4) * 8;
        const float sg = (g == 2) ? K2 : -K;
#pragma unroll
        for (int tt = 0; tt < 2; ++tt) {
            const int uu = 8 * w + 4 * tt + (m >> 2);
            const float* row = &W_hh[(size_t)(g * HID + uu) * HID];
#pragma unroll
            for (int q = 0; q < 2; ++q) {
                const float* p = row + 32 * q + kb;
                half8 hf;
#pragma unroll
                for (int i = 0; i < 8; ++i) hf[i] = (_Float16)(sg * p[i]);
                af[tt][q] = hf;
            }
        }
    }

    // ---- lane role: col c, batch b (8 real rows), tile-select dup, unit u ----
    const int c   = L & 15;
    const int b   = c & 7;
    const int dup = (c >> 3) & 1;
    const int rg  = L >> 4;
    // lane's act: unit u = 8w + 4*dup + rg; one activation per lane.

    // per-tile pre-gate params, pre-scaled into exp2 domain
    float wihT[2][4], biasT[2][4];
#pragma unroll
    for (int tt = 0; tt < 2; ++tt) {
        const int ut = 8 * w + 4 * tt + rg;
#pragma unroll
        for (int g = 0; g < 4; ++g) {
            const float s = (g == 2) ? K2 : -K;
            wihT[tt][g]  = s * W_ih[g * HID + ut];
            biasT[tt][g] = s * (b_ih[g * HID + ut] + b_hh[g * HID + ut]);
        }
    }

    const float* xrow = &xs[b][0];
    const int koff = rg * 8;
    const _Float16* h0r = &hbuf[0][b][0];
    _Float16*       h0w = &hbuf[0][0][0];
    const _Float16* h1r = &hbuf[1][b][0];
    _Float16*       h1w = &hbuf[1][0][0];
    const int widx = b * 80 + (8 * w + 4 * dup + rg); // write offset
    float S = 0.0f;                  // state: S = 2K * c

    // pre-gate C_in for the CURRENT step, produced one step ahead
    f32x4 cp0, cp1;

    __syncthreads();

    // step: consumes cp0/cp1 (C_in for step t), produces cp0/cp1 for t+1
    // from xnext during the exp2 shadow.
    auto step = [&](const _Float16* hin, _Float16* hout, float xnext) {
        half8 b0 = *(const half8*)(hin + koff);
        half8 b1 = *(const half8*)(hin + koff + 32);

        // two independent depth-2 chains; acc carries the pre-gate.
        // b0-only pair first: MFMA starts at lgkmcnt(1).
        f32x4 t0 = __builtin_amdgcn_mfma_f32_16x16x32_f16(af[0][0], b0, cp0, 0, 0, 0);
        f32x4 t1 = __builtin_amdgcn_mfma_f32_16x16x32_f16(af[1][0], b0, cp1, 0, 0, 0);
        t0 = __builtin_amdgcn_mfma_f32_16x16x32_f16(af[0][1], b1, t0, 0, 0, 0);
        t1 = __builtin_amdgcn_mfma_f32_16x16x32_f16(af[1][1], b1, t1, 0, 0, 0);

        // single 4-wide tile select
        f32x4 dS;
#pragma unroll
        for (int g = 0; g < 4; ++g) dS[g] = dup ? t1[g] : t0[g];

        // args already scaled: -K*a (i,f,o), +2K*a (g)
        const float ei = exp2_fast(dS[0]);
        const float ef = exp2_fast(dS[1]);
        const float eg = exp2_fast(dS[2]);
        const float eo = exp2_fast(dS[3]);

        // next step's pre-gates, in the exp2 shadow (x-only dependence)
#pragma unroll
        for (int g = 0; g < 4; ++g) {
            cp0[g] = fmaf(xnext, wihT[0][g], biasT[0][g]);
            cp1[g] = fmaf(xnext, wihT[1][g], biasT[1][g]);
        }

        // merged-ratio cell on S = 2K*c: 2 rcp total
        const float A1  = 1.0f + ei;
        const float B1  = 1.0f + eg;
        const float E1  = 1.0f + ef;
        const float C1K = fmaf(eg, K2, -K2);     // 2K*(eg-1)
        const float Pig = A1 * B1;               // (1+ei)(1+eg)
        const float Dde = E1 * Pig;              // common denominator
        const float CEK = C1K * E1;
        const float num = fmaf(S, Pig, CEK);
        S = num * rcp_fast(Dde);                 // S' = 2K*(gf*c + gi*gg)
        const float ec = exp2_fast(S);
        const float F1 = 1.0f + eo;
        const float G1 = 1.0f + ec;
        const float H1 = ec - 1.0f;
        const float hv = H1 * rcp_fast(F1 * G1); // go * tanh(c')
        hout[widx] = (_Float16)hv;  // one write per lane, 64 unique (b,u)
    };

    // prologue: C_in for t=0
    {
        const float x0 = xrow[0];
#pragma unroll
        for (int g = 0; g < 4; ++g) {
            cp0[g] = fmaf(x0, wihT[0][g], biasT[0][g]);
            cp1[g] = fmaf(x0, wihT[1][g], biasT[1][g]);
        }
    }

    float4 xq = *(const float4*)&xrow[0];
    for (int t = 0; t < TLEN; t += 4) {
        // next quad's x, loaded at quad top (max lead; off the barrier burst)
        const float4 xq_n = *(const float4*)&xrow[t + 4]; // in-bounds: 516 pad
        step(h0r, h1w, xq.y);        // step t,   builds pre(t+1)
        __syncthreads();
        step(h1r, h0w, xq.z);        // step t+1, builds pre(t+2)
        __syncthreads();
        step(h0r, h1w, xq.w);        // step t+2, builds pre(t+3)
        __syncthreads();
        step(h1r, h0w, xq_n.x);      // step t+3, builds pre(t+4)
        __syncthreads();
        xq = xq_n;
    }

    // ---- epilogue: wave w reduces batch row w (final h in hbuf[0]) ----
    float pv = (float)hbuf[0][w][L] * W_d[L];
#pragma unroll
    for (int off = 32; off > 0; off >>= 1)
        pv += __shfl_xor(pv, off, 64);
    if (L == 0)
        out[r0 + w] = pv + b_d[0];
}

extern "C" void kernel_launch(void* const* d_in, const int* in_sizes, int n_in,
                              void* d_out, int out_size, void* d_ws, size_t ws_size,
                              hipStream_t stream) {
    const float* x    = (const float*)d_in[0];
    const float* W_ih = (const float*)d_in[1];
    const float* W_hh = (const float*)d_in[2];
    const float* b_ih = (const float*)d_in[3];
    const float* b_hh = (const float*)d_in[4];
    const float* W_d  = (const float*)d_in[5];
    const float* b_d  = (const float*)d_in[6];
    float* out = (float*)d_out;

    dim3 grid(256);    // 2048 / 8 batch rows per block -> 1 block/CU
    dim3 block(512);   // 8 waves = 2/SIMD (best measured shape)
    lstm_r20<<<grid, block, 0, stream>>>(x, W_ih, W_hh, b_ih, b_hh, W_d, b_d, out);
}

// Round 10
// 204.574 us; speedup vs baseline: 1.3516x; 1.0030x over previous
//
#include <hip/hip_runtime.h>

#define TLEN 512
#define HID  64

typedef _Float16 half8 __attribute__((ext_vector_type(8)));
typedef float    f32x4 __attribute__((ext_vector_type(4)));

__device__ __forceinline__ float rcp_fast(float x) { return __builtin_amdgcn_rcpf(x); }
__device__ __forceinline__ float exp2_fast(float x) {
#if __has_builtin(__builtin_amdgcn_exp2f)
    return __builtin_amdgcn_exp2f(x);
#else
    float r; asm("v_exp_f32 %0, %1" : "=v"(r) : "v"(x)); return r;
#endif
}

// R21 = R15 (157.6 us, best measured) with hbuf stride 80 -> 88.
// Bank math: write bank = ((stride/2)*b + u/2) mod 32. stride 80 -> 40b:
// 8b mod 32 collides b with b+4 => ~4-way conflict on the pre-barrier
// ds_write (the 2.1M counter). stride 88 -> 44b: 12b mod 32 gives 8
// disjoint 4-bank windows, 2 lanes/bank (free, m136); odd/even-u lane
// pairs share one dword (broadcast-merge). Read starts (12b+4rg) no worse
// than stride 80. Single-variable change on the optimum; everything else
// is exactly R15 (R16/R19/R20 schedule experiments all reverted).
__global__ __launch_bounds__(512) __attribute__((amdgpu_waves_per_eu(2, 2)))
void lstm_r21(const float* __restrict__ x,
              const float* __restrict__ W_ih,
              const float* __restrict__ W_hh,
              const float* __restrict__ b_ih,
              const float* __restrict__ b_hh,
              const float* __restrict__ W_d,
              const float* __restrict__ b_d,
              float* __restrict__ out) {
    __shared__ __align__(16) float    xs[8][516];     // 8 x rows
    __shared__ __align__(16) _Float16 hbuf[2][8][88]; // ping-pong h, pad 88

    const int tid = threadIdx.x;
    const int L   = tid & 63;
    const int w   = tid >> 6;        // wave 0..7, owns units [8w, 8w+8)
    const int r0  = blockIdx.x * 8;

    // ---- stage x rows (float4) ----
    for (int i = tid; i < 8 * 128; i += 512) {
        const int r = i >> 7, t4 = (i & 127) * 4;
        *(float4*)&xs[r][t4] = *(const float4*)&x[(size_t)(r0 + r) * TLEN + t4];
    }
    // ---- zero both h buffers (h0 = 0) ----
    for (int i = tid; i < 2 * 8 * 88; i += 512)
        ((_Float16*)hbuf)[i] = (_Float16)0.0f;

    const float K  = 1.44269504f;    // log2 e
    const float K2 = 2.0f * K;

    // ---- resident A-frags: A[m][k], m=L&15, k=32q+(L>>4)*8+i ----
    // tile tt -> unit 8w+4tt+(m>>2), gate m&3 (i,f,g,o)
    // Gate scale folded into A: s = -K (i,f,o), +2K (g).
    half8 af[2][2];
    {
        const int m = L & 15;
        const int g = m & 3;
        const int kb = (L >> 4) * 8;
        const float sg = (g == 2) ? K2 : -K;
#pragma unroll
        for (int tt = 0; tt < 2; ++tt) {
            const int uu = 8 * w + 4 * tt + (m >> 2);
            const float* row = &W_hh[(size_t)(g * HID + uu) * HID];
#pragma unroll
            for (int q = 0; q < 2; ++q) {
                const float* p = row + 32 * q + kb;
                half8 hf;
#pragma unroll
                for (int i = 0; i < 8; ++i) hf[i] = (_Float16)(sg * p[i]);
                af[tt][q] = hf;
            }
        }
    }

    // ---- lane role: col c, batch b (8 real rows), tile-select dup, unit u ----
    const int c   = L & 15;
    const int b   = c & 7;
    const int dup = (c >> 3) & 1;
    const int rg  = L >> 4;
    // lane's act: unit u = 8w + 4*dup + rg; one activation per lane.

    // per-tile pre-gate params, pre-scaled into exp2 domain (both tiles:
    // C_in must be valid for the whole 16x16 tile, not just selected lanes)
    float wihT[2][4], biasT[2][4];
#pragma unroll
    for (int tt = 0; tt < 2; ++tt) {
        const int ut = 8 * w + 4 * tt + rg;
#pragma unroll
        for (int g = 0; g < 4; ++g) {
            const float s = (g == 2) ? K2 : -K;
            wihT[tt][g]  = s * W_ih[g * HID + ut];
            biasT[tt][g] = s * (b_ih[g * HID + ut] + b_hh[g * HID + ut]);
        }
    }

    const float* xrow = &xs[b][0];
    const int koff = rg * 8;
    const _Float16* h0r = &hbuf[0][b][0];
    _Float16*       h0w = &hbuf[0][0][0];
    const _Float16* h1r = &hbuf[1][b][0];
    _Float16*       h1w = &hbuf[1][0][0];
    const int widx = b * 88 + (8 * w + 4 * dup + rg); // write offset
    float S = 0.0f;                  // state: S = 2K * c

    __syncthreads();

    auto step = [&](const _Float16* hin, _Float16* hout, float xt) {
        // pre-gates ride in the MFMA accumulator (8 fma, both tiles)
        f32x4 c0, c1;
#pragma unroll
        for (int g = 0; g < 4; ++g) {
            c0[g] = fmaf(xt, wihT[0][g], biasT[0][g]);
            c1[g] = fmaf(xt, wihT[1][g], biasT[1][g]);
        }

        half8 b0 = *(const half8*)(hin + koff);
        half8 b1 = *(const half8*)(hin + koff + 32);

        // two independent chains of depth 2; acc carries the pre-gate.
        // b0-only pair first: MFMA starts at lgkmcnt(1).
        f32x4 t0 = __builtin_amdgcn_mfma_f32_16x16x32_f16(af[0][0], b0, c0, 0, 0, 0);
        f32x4 t1 = __builtin_amdgcn_mfma_f32_16x16x32_f16(af[1][0], b0, c1, 0, 0, 0);
        t0 = __builtin_amdgcn_mfma_f32_16x16x32_f16(af[0][1], b1, t0, 0, 0, 0);
        t1 = __builtin_amdgcn_mfma_f32_16x16x32_f16(af[1][1], b1, t1, 0, 0, 0);

        // single 4-wide tile select
        f32x4 dS;
#pragma unroll
        for (int g = 0; g < 4; ++g) dS[g] = dup ? t1[g] : t0[g];

        // args already scaled: -K*a (i,f,o), +2K*a (g)
        const float ei = exp2_fast(dS[0]);
        const float ef = exp2_fast(dS[1]);
        const float eg = exp2_fast(dS[2]);
        const float eo = exp2_fast(dS[3]);

        // merged-ratio cell on S = 2K*c: 2 rcp total
        const float A1  = 1.0f + ei;
        const float B1  = 1.0f + eg;
        const float E1  = 1.0f + ef;
        const float C1K = fmaf(eg, K2, -K2);     // 2K*(eg-1)
        const float Pig = A1 * B1;               // (1+ei)(1+eg)
        const float Dde = E1 * Pig;              // common denominator
        const float CEK = C1K * E1;
        const float num = fmaf(S, Pig, CEK);
        S = num * rcp_fast(Dde);                 // S' = 2K*(gf*c + gi*gg)
        const float ec = exp2_fast(S);
        const float F1 = 1.0f + eo;
        const float G1 = 1.0f + ec;
        const float H1 = ec - 1.0f;
        const float hv = H1 * rcp_fast(F1 * G1); // go * tanh(c')
        hout[widx] = (_Float16)hv;  // one write per lane, 64 unique (b,u)
    };

    for (int t = 0; t < TLEN; t += 4) {
        // x register-blocking: one b128 read covers 4 steps (16B-aligned)
        const float4 xq = *(const float4*)&xrow[t];
        step(h0r, h1w, xq.x);
        __syncthreads();
        step(h1r, h0w, xq.y);
        __syncthreads();
        step(h0r, h1w, xq.z);
        __syncthreads();
        step(h1r, h0w, xq.w);
        __syncthreads();
    }

    // ---- epilogue: wave w reduces batch row w (final h in hbuf[0]) ----
    float pv = (float)hbuf[0][w][L] * W_d[L];
#pragma unroll
    for (int off = 32; off > 0; off >>= 1)
        pv += __shfl_xor(pv, off, 64);
    if (L == 0)
        out[r0 + w] = pv + b_d[0];
}

extern "C" void kernel_launch(void* const* d_in, const int* in_sizes, int n_in,
                              void* d_out, int out_size, void* d_ws, size_t ws_size,
                              hipStream_t stream) {
    const float* x    = (const float*)d_in[0];
    const float* W_ih = (const float*)d_in[1];
    const float* W_hh = (const float*)d_in[2];
    const float* b_ih = (const float*)d_in[3];
    const float* b_hh = (const float*)d_in[4];
    const float* W_d  = (const float*)d_in[5];
    const float* b_d  = (const float*)d_in[6];
    float* out = (float*)d_out;

    dim3 grid(256);    // 2048 / 8 batch rows per block -> 1 block/CU
    dim3 block(512);   // 8 waves = 2/SIMD (best measured shape)
    lstm_r21<<<grid, block, 0, stream>>>(x, W_ih, W_hh, b_ih, b_hh, W_d, b_d, out);
}

// Round 11
// 202.778 us; speedup vs baseline: 1.3636x; 1.0089x over previous
//
#include <hip/hip_runtime.h>

#define TLEN 512
#define HID  64

typedef _Float16 half8 __attribute__((ext_vector_type(8)));
typedef float    f32x4 __attribute__((ext_vector_type(4)));

__device__ __forceinline__ float rcp_fast(float x) { return __builtin_amdgcn_rcpf(x); }
__device__ __forceinline__ float exp2_fast(float x) {
#if __has_builtin(__builtin_amdgcn_exp2f)
    return __builtin_amdgcn_exp2f(x);
#else
    float r; asm("v_exp_f32 %0, %1" : "=v"(r) : "v"(x)); return r;
#endif
}

// R22 = R15 restored verbatim (best measured: 157.6 us rocprof). Final form.
// Design (each element measured-optimal over R11-R21):
//  - 256 blocks x 8 waves (2/SIMD), block owns 8 rows, dup2 (MFMA floor at
//    full-chip census: 1 act/lane needs 2048 waves; 16 cols = 8 real x 2 dup)
//  - pre-gate rides in MFMA C_in (kills merge-adds; R15 win)
//  - merged-ratio cell, 5 exp2 + 2 rcp (algebraic floor; R14 win), scales
//    folded into f16 A / wih / bias
//  - hbuf stride 80 (conflict optimum of {72,88}: 2.1M vs 8.4M)
//  - plain 4-step x register-blocking, one barrier per step (forced by
//    all-units K=64 dependency)
// Rejected by measurement: dup4/2-block (R12/R18), 1 wave/SIMD (R13),
// setprio (R16), 32x32 MFMA (R17: 32cyc/SIMD-issue), role-split (R19),
// prefix pipelining (R20), stride 88 (R21).
// Step = 736 cyc = 472 issue (VALU 342 + MFMA 131, counter-verified) +
// 264 serial-recurrence latency (exchange round-trip + MFMA + trans chain).
__global__ __launch_bounds__(512) __attribute__((amdgpu_waves_per_eu(2, 2)))
void lstm_mfma8(const float* __restrict__ x,
                const float* __restrict__ W_ih,
                const float* __restrict__ W_hh,
                const float* __restrict__ b_ih,
                const float* __restrict__ b_hh,
                const float* __restrict__ W_d,
                const float* __restrict__ b_d,
                float* __restrict__ out) {
    __shared__ __align__(16) float    xs[8][516];     // 8 x rows
    __shared__ __align__(16) _Float16 hbuf[2][8][80]; // ping-pong h, pad 80

    const int tid = threadIdx.x;
    const int L   = tid & 63;
    const int w   = tid >> 6;        // wave 0..7, owns units [8w, 8w+8)
    const int r0  = blockIdx.x * 8;

    // ---- stage x rows (float4) ----
    for (int i = tid; i < 8 * 128; i += 512) {
        const int r = i >> 7, t4 = (i & 127) * 4;
        *(float4*)&xs[r][t4] = *(const float4*)&x[(size_t)(r0 + r) * TLEN + t4];
    }
    // ---- zero both h buffers (h0 = 0) ----
    for (int i = tid; i < 2 * 8 * 80; i += 512)
        ((_Float16*)hbuf)[i] = (_Float16)0.0f;

    const float K  = 1.44269504f;    // log2 e
    const float K2 = 2.0f * K;

    // ---- resident A-frags: A[m][k], m=L&15, k=32q+(L>>4)*8+i ----
    // tile tt -> unit 8w+4tt+(m>>2), gate m&3 (i,f,g,o)
    // Gate scale folded into A: s = -K (i,f,o), +2K (g).
    half8 af[2][2];
    {
        const int m = L & 15;
        const int g = m & 3;
        const int kb = (L >> 4) * 8;
        const float sg = (g == 2) ? K2 : -K;
#pragma unroll
        for (int tt = 0; tt < 2; ++tt) {
            const int uu = 8 * w + 4 * tt + (m >> 2);
            const float* row = &W_hh[(size_t)(g * HID + uu) * HID];
#pragma unroll
            for (int q = 0; q < 2; ++q) {
                const float* p = row + 32 * q + kb;
                half8 hf;
#pragma unroll
                for (int i = 0; i < 8; ++i) hf[i] = (_Float16)(sg * p[i]);
                af[tt][q] = hf;
            }
        }
    }

    // ---- lane role: col c, batch b (8 real rows), tile-select dup, unit u ----
    const int c   = L & 15;
    const int b   = c & 7;
    const int dup = (c >> 3) & 1;
    const int rg  = L >> 4;
    // lane's act: unit u = 8w + 4*dup + rg; one activation per lane.

    // per-tile pre-gate params, pre-scaled into exp2 domain (both tiles:
    // C_in must be valid for the whole 16x16 tile, not just selected lanes)
    float wihT[2][4], biasT[2][4];
#pragma unroll
    for (int tt = 0; tt < 2; ++tt) {
        const int ut = 8 * w + 4 * tt + rg;
#pragma unroll
        for (int g = 0; g < 4; ++g) {
            const float s = (g == 2) ? K2 : -K;
            wihT[tt][g]  = s * W_ih[g * HID + ut];
            biasT[tt][g] = s * (b_ih[g * HID + ut] + b_hh[g * HID + ut]);
        }
    }

    const float* xrow = &xs[b][0];
    const int koff = rg * 8;
    const _Float16* h0r = &hbuf[0][b][0];
    _Float16*       h0w = &hbuf[0][0][0];
    const _Float16* h1r = &hbuf[1][b][0];
    _Float16*       h1w = &hbuf[1][0][0];
    const int widx = b * 80 + (8 * w + 4 * dup + rg); // write offset
    float S = 0.0f;                  // state: S = 2K * c

    __syncthreads();

    auto step = [&](const _Float16* hin, _Float16* hout, float xt) {
        // pre-gates ride in the MFMA accumulator (8 fma, both tiles)
        f32x4 c0, c1;
#pragma unroll
        for (int g = 0; g < 4; ++g) {
            c0[g] = fmaf(xt, wihT[0][g], biasT[0][g]);
            c1[g] = fmaf(xt, wihT[1][g], biasT[1][g]);
        }

        half8 b0 = *(const half8*)(hin + koff);
        half8 b1 = *(const half8*)(hin + koff + 32);

        // two independent chains of depth 2; acc carries the pre-gate
        f32x4 t0 = __builtin_amdgcn_mfma_f32_16x16x32_f16(af[0][0], b0, c0, 0, 0, 0);
        f32x4 t1 = __builtin_amdgcn_mfma_f32_16x16x32_f16(af[1][0], b0, c1, 0, 0, 0);
        t0 = __builtin_amdgcn_mfma_f32_16x16x32_f16(af[0][1], b1, t0, 0, 0, 0);
        t1 = __builtin_amdgcn_mfma_f32_16x16x32_f16(af[1][1], b1, t1, 0, 0, 0);

        // single 4-wide select (was 8 cndmask + 8 adds)
        f32x4 dS;
#pragma unroll
        for (int g = 0; g < 4; ++g) dS[g] = dup ? t1[g] : t0[g];

        // args already scaled: -K*a for i,f,o; +2K*a for g
        const float ei = exp2_fast(dS[0]);
        const float ef = exp2_fast(dS[1]);
        const float eg = exp2_fast(dS[2]);
        const float eo = exp2_fast(dS[3]);

        // merged-ratio cell on S = 2K*c: 2 rcp total
        const float A1  = 1.0f + ei;
        const float B1  = 1.0f + eg;
        const float E1  = 1.0f + ef;
        const float C1K = fmaf(eg, K2, -K2);     // 2K*(eg-1)
        const float Pig = A1 * B1;               // (1+ei)(1+eg)
        const float Dde = E1 * Pig;              // common denominator
        const float CEK = C1K * E1;
        const float num = fmaf(S, Pig, CEK);
        S = num * rcp_fast(Dde);                 // S' = 2K*(gf*c + gi*gg)
        const float ec = exp2_fast(S);
        const float F1 = 1.0f + eo;
        const float G1 = 1.0f + ec;
        const float H1 = ec - 1.0f;
        const float hv = H1 * rcp_fast(F1 * G1); // go * tanh(c')
        hout[widx] = (_Float16)hv;  // one write per lane, 64 unique (b,u)
    };

    for (int t = 0; t < TLEN; t += 4) {
        // x register-blocking: one b128 read covers 4 steps (16B-aligned)
        const float4 xq = *(const float4*)&xrow[t];
        step(h0r, h1w, xq.x);
        __syncthreads();
        step(h1r, h0w, xq.y);
        __syncthreads();
        step(h0r, h1w, xq.z);
        __syncthreads();
        step(h1r, h0w, xq.w);
        __syncthreads();
    }

    // ---- epilogue: wave w reduces batch row w (final h in hbuf[0]) ----
    float pv = (float)hbuf[0][w][L] * W_d[L];
#pragma unroll
    for (int off = 32; off > 0; off >>= 1)
        pv += __shfl_xor(pv, off, 64);
    if (L == 0)
        out[r0 + w] = pv + b_d[0];
}

extern "C" void kernel_launch(void* const* d_in, const int* in_sizes, int n_in,
                              void* d_out, int out_size, void* d_ws, size_t ws_size,
                              hipStream_t stream) {
    const float* x    = (const float*)d_in[0];
    const float* W_ih = (const float*)d_in[1];
    const float* W_hh = (const float*)d_in[2];
    const float* b_ih = (const float*)d_in[3];
    const float* b_hh = (const float*)d_in[4];
    const float* W_d  = (const float*)d_in[5];
    const float* b_d  = (const float*)d_in[6];
    float* out = (float*)d_out;

    dim3 grid(256);    // 2048 / 8 batch rows per block -> 1 block/CU
    dim3 block(512);   // 8 waves = 2/SIMD (best measured shape)
    lstm_mfma8<<<grid, block, 0, stream>>>(x, W_ih, W_hh, b_ih, b_hh, W_d, b_d, out);
}